// Round 1
// baseline (289.240 us; speedup 1.0000x reference)
//
#include <hip/hip_runtime.h>

// Problem dims (fixed by reference)
#define C_DIM 2048
#define T_DIM 1024
#define R_DIM 32
#define K_DIM 128

#define NC 8                    // c-chunks for kernel B parallelism
#define KG 4                    // k's per thread (amortize uv load)
#define CCHUNK (C_DIM / NC)     // 256

// Kernel A: uv[c][t] = sum_r U[c][t][r] * V[r][t]
// U is (C,T,R): per-thread R=32 floats are contiguous -> 8x float4.
// V is (R,T): lanes with consecutive t are coalesced; V is 128 KiB, L2-resident.
__global__ void uv_kernel(const float* __restrict__ U, const float* __restrict__ V,
                          float* __restrict__ uv) {
    int idx = blockIdx.x * blockDim.x + threadIdx.x;  // idx = c*T + t
    int t = idx & (T_DIM - 1);
    const float* u = U + (size_t)idx * R_DIM;
    float acc = 0.f;
#pragma unroll
    for (int r = 0; r < R_DIM; r += 4) {
        float4 uq = *reinterpret_cast<const float4*>(u + r);
        acc += uq.x * V[(r + 0) * T_DIM + t];
        acc += uq.y * V[(r + 1) * T_DIM + t];
        acc += uq.z * V[(r + 2) * T_DIM + t];
        acc += uq.w * V[(r + 3) * T_DIM + t];
    }
    uv[idx] = acc;
}

// Kernel B: partial[chunk][k][t] = sum_{c in chunk} uv[c][t] * X[k][c][t]
// Each thread: one (chunk, k-group of 4, t). X loads coalesced over t (lane dim).
__global__ void partial_kernel(const float* __restrict__ X, const float* __restrict__ uv,
                               float* __restrict__ part) {
    int tid = blockIdx.x * blockDim.x + threadIdx.x;
    int t     = tid & (T_DIM - 1);
    int kg    = (tid >> 10) & ((K_DIM / KG) - 1);   // 0..31
    int chunk = tid >> 15;                          // 0..NC-1
    int k0 = kg * KG;
    int c0 = chunk * CCHUNK;

    const size_t kstride = (size_t)C_DIM * T_DIM;   // stride between k planes
    const float* xbase = X + (size_t)k0 * kstride + (size_t)c0 * T_DIM + t;
    const float* uvp   = uv + (size_t)c0 * T_DIM + t;

    float acc0 = 0.f, acc1 = 0.f, acc2 = 0.f, acc3 = 0.f;
#pragma unroll 4
    for (int c = 0; c < CCHUNK; ++c) {
        float w = uvp[(size_t)c * T_DIM];
        size_t off = (size_t)c * T_DIM;
        acc0 += w * xbase[off];
        acc1 += w * xbase[off + kstride];
        acc2 += w * xbase[off + 2 * kstride];
        acc3 += w * xbase[off + 3 * kstride];
    }
    float* p = part + ((size_t)chunk * K_DIM + k0) * T_DIM + t;
    p[0 * T_DIM] = acc0;
    p[1 * T_DIM] = acc1;
    p[2 * T_DIM] = acc2;
    p[3 * T_DIM] = acc3;
}

// Kernel C: out[k][t] = sum_chunk partial[chunk][k][t]
__global__ void reduce_kernel(const float* __restrict__ part, float* __restrict__ out) {
    int tid = blockIdx.x * blockDim.x + threadIdx.x;  // k*T + t
    float acc = 0.f;
#pragma unroll
    for (int ch = 0; ch < NC; ++ch)
        acc += part[(size_t)ch * K_DIM * T_DIM + tid];
    out[tid] = acc;
}

extern "C" void kernel_launch(void* const* d_in, const int* in_sizes, int n_in,
                              void* d_out, int out_size, void* d_ws, size_t ws_size,
                              hipStream_t stream) {
    // inputs: [0]=recording_index (unused), [1]=X (K,C,T), [2]=U (C,T,R), [3]=V (R,T)
    const float* X = (const float*)d_in[1];
    const float* U = (const float*)d_in[2];
    const float* V = (const float*)d_in[3];
    float* out = (float*)d_out;

    float* uv   = (float*)d_ws;                          // C*T floats = 8 MiB
    float* part = uv + (size_t)C_DIM * T_DIM;            // NC*K*T floats = 4 MiB

    uv_kernel<<<C_DIM * T_DIM / 256, 256, 0, stream>>>(U, V, uv);
    partial_kernel<<<NC * (K_DIM / KG) * T_DIM / 256, 256, 0, stream>>>(X, uv, part);
    reduce_kernel<<<K_DIM * T_DIM / 256, 256, 0, stream>>>(part, out);
}

// Round 2
// 277.628 us; speedup vs baseline: 1.0418x; 1.0418x over previous
//
#include <hip/hip_runtime.h>

// Problem dims (fixed by reference)
#define C_DIM 2048
#define T_DIM 1024
#define R_DIM 32
#define K_DIM 128

#define NC 16                   // c-chunks for kernel B parallelism
#define KG 4                    // k's per thread (amortize uv load)
#define CCHUNK (C_DIM / NC)     // 128

// Kernel A: uv[c][t] = sum_r U[c][t][r] * V[r][t]
// U is (C,T,R): per-thread R=32 floats are contiguous -> 8x float4; a wave's
// 8 unrolled loads fully consume a contiguous 8 KiB span. V is 128 KiB,
// L2-resident; lanes (consecutive t) coalesce.
__global__ void uv_kernel(const float* __restrict__ U, const float* __restrict__ V,
                          float* __restrict__ uv) {
    int idx = blockIdx.x * blockDim.x + threadIdx.x;  // idx = c*T + t
    int t = idx & (T_DIM - 1);
    const float* u = U + (size_t)idx * R_DIM;
    float acc = 0.f;
#pragma unroll
    for (int r = 0; r < R_DIM; r += 4) {
        float4 uq = *reinterpret_cast<const float4*>(u + r);
        acc += uq.x * V[(r + 0) * T_DIM + t];
        acc += uq.y * V[(r + 1) * T_DIM + t];
        acc += uq.z * V[(r + 2) * T_DIM + t];
        acc += uq.w * V[(r + 3) * T_DIM + t];
    }
    uv[idx] = acc;
}

// Kernel B: partial[chunk][k][t] = sum_{c in chunk} uv[c][t] * X[k][c][t]
// Vectorized x4 over t: every load/store is float4 (1 KiB per wave-instr).
// Each thread: one (chunk, k-group of KG, t-quad).
__global__ void partial_kernel(const float* __restrict__ X, const float* __restrict__ uv,
                               float* __restrict__ part) {
    int tid = blockIdx.x * blockDim.x + threadIdx.x;
    int t4    = tid & (T_DIM / 4 - 1);              // 0..255, t0 = 4*t4
    int kg    = (tid >> 8) & ((K_DIM / KG) - 1);    // 0..31
    int chunk = tid >> 13;                          // 0..NC-1
    int t0 = t4 * 4;
    int k0 = kg * KG;
    int c0 = chunk * CCHUNK;

    const size_t kstride = (size_t)C_DIM * T_DIM;   // stride between k planes
    const float* xb  = X + (size_t)k0 * kstride + (size_t)c0 * T_DIM + t0;
    const float* uvp = uv + (size_t)c0 * T_DIM + t0;

    float4 a0 = make_float4(0.f, 0.f, 0.f, 0.f);
    float4 a1 = a0, a2 = a0, a3 = a0;

#pragma unroll 4
    for (int c = 0; c < CCHUNK; ++c) {
        size_t off = (size_t)c * T_DIM;
        float4 w  = *reinterpret_cast<const float4*>(uvp + off);
        float4 x0 = *reinterpret_cast<const float4*>(xb + off);
        float4 x1 = *reinterpret_cast<const float4*>(xb + off + kstride);
        float4 x2 = *reinterpret_cast<const float4*>(xb + off + 2 * kstride);
        float4 x3 = *reinterpret_cast<const float4*>(xb + off + 3 * kstride);
        a0.x += w.x * x0.x; a0.y += w.y * x0.y; a0.z += w.z * x0.z; a0.w += w.w * x0.w;
        a1.x += w.x * x1.x; a1.y += w.y * x1.y; a1.z += w.z * x1.z; a1.w += w.w * x1.w;
        a2.x += w.x * x2.x; a2.y += w.y * x2.y; a2.z += w.z * x2.z; a2.w += w.w * x2.w;
        a3.x += w.x * x3.x; a3.y += w.y * x3.y; a3.z += w.z * x3.z; a3.w += w.w * x3.w;
    }
    float* p = part + ((size_t)chunk * K_DIM + k0) * T_DIM + t0;
    *reinterpret_cast<float4*>(p + 0 * T_DIM) = a0;
    *reinterpret_cast<float4*>(p + 1 * T_DIM) = a1;
    *reinterpret_cast<float4*>(p + 2 * T_DIM) = a2;
    *reinterpret_cast<float4*>(p + 3 * T_DIM) = a3;
}

// Kernel C: out[k][t] = sum_chunk partial[chunk][k][t], float4 over t
__global__ void reduce_kernel(const float* __restrict__ part, float* __restrict__ out) {
    int tid = blockIdx.x * blockDim.x + threadIdx.x;  // (k*T + t)/4
    size_t o = (size_t)tid * 4;
    float4 acc = make_float4(0.f, 0.f, 0.f, 0.f);
#pragma unroll
    for (int ch = 0; ch < NC; ++ch) {
        float4 v = *reinterpret_cast<const float4*>(part + (size_t)ch * K_DIM * T_DIM + o);
        acc.x += v.x; acc.y += v.y; acc.z += v.z; acc.w += v.w;
    }
    *reinterpret_cast<float4*>(out + o) = acc;
}

extern "C" void kernel_launch(void* const* d_in, const int* in_sizes, int n_in,
                              void* d_out, int out_size, void* d_ws, size_t ws_size,
                              hipStream_t stream) {
    // inputs: [0]=recording_index (unused), [1]=X (K,C,T), [2]=U (C,T,R), [3]=V (R,T)
    const float* X = (const float*)d_in[1];
    const float* U = (const float*)d_in[2];
    const float* V = (const float*)d_in[3];
    float* out = (float*)d_out;

    float* uv   = (float*)d_ws;                          // C*T floats = 8 MiB
    float* part = uv + (size_t)C_DIM * T_DIM;            // NC*K*T floats = 8 MiB

    uv_kernel<<<C_DIM * T_DIM / 256, 256, 0, stream>>>(U, V, uv);
    partial_kernel<<<NC * (K_DIM / KG) * (T_DIM / 4) / 256, 256, 0, stream>>>(X, uv, part);
    reduce_kernel<<<K_DIM * T_DIM / 4 / 256, 256, 0, stream>>>(part, out);
}